// Round 1
// baseline (1969.878 us; speedup 1.0000x reference)
//
#include <hip/hip_runtime.h>

#define NLOW 100000
#define NHIGH 100000
#define EDG 1600000
#define DD 32
#define LAY 2

static inline int cdiv(int a, int b) { return (a + b - 1) / b; }

// ---------------- utility kernels ----------------
__global__ void k_zero_i(int* p, int n) {
    int i = blockIdx.x * blockDim.x + threadIdx.x;
    if (i < n) p[i] = 0;
}
__global__ void k_zero_f(float* p, int n) {
    int i = blockIdx.x * blockDim.x + threadIdx.x;
    if (i < n) p[i] = 0.f;
}
__global__ void k_copy_i(int* d, const int* __restrict__ s, int n) {
    int i = blockIdx.x * blockDim.x + threadIdx.x;
    if (i < n) d[i] = s[i];
}

// ---------------- CSR build ----------------
__global__ void k_count(const int* __restrict__ dst, int n, int* __restrict__ counts) {
    int i = blockIdx.x * blockDim.x + threadIdx.x;
    if (i < n) atomicAdd(&counts[dst[i]], 1);
}

// per-block inclusive scan over chunks of 1024 (256 thr x 4), writes rowptr[i+1]
__global__ void k_scan1(const int* __restrict__ in, int n, int* __restrict__ rowptr,
                        int* __restrict__ bsums) {
    __shared__ int sh[256];
    int tid = threadIdx.x;
    int base = blockIdx.x * 1024;
    int v[4];
    int s = 0;
#pragma unroll
    for (int k = 0; k < 4; k++) {
        int idx = base + tid * 4 + k;
        v[k] = (idx < n) ? in[idx] : 0;
        s += v[k];
    }
    sh[tid] = s;
    __syncthreads();
    for (int off = 1; off < 256; off <<= 1) {
        int t = (tid >= off) ? sh[tid - off] : 0;
        __syncthreads();
        sh[tid] += t;
        __syncthreads();
    }
    int run = (tid > 0) ? sh[tid - 1] : 0;
#pragma unroll
    for (int k = 0; k < 4; k++) {
        int idx = base + tid * 4 + k;
        run += v[k];
        if (idx < n) rowptr[idx + 1] = run;
    }
    if (tid == 255) bsums[blockIdx.x] = sh[255];
}

// single-block exclusive scan of block sums (B <= 256)
__global__ void k_scan2(int* bsums, int B) {
    __shared__ int sh[256];
    int tid = threadIdx.x;
    int v = (tid < B) ? bsums[tid] : 0;
    sh[tid] = v;
    __syncthreads();
    for (int off = 1; off < 256; off <<= 1) {
        int t = (tid >= off) ? sh[tid - off] : 0;
        __syncthreads();
        sh[tid] += t;
        __syncthreads();
    }
    if (tid < B) bsums[tid] = sh[tid] - v;  // exclusive
}

__global__ void k_scan3(int* rowptr, int n, const int* __restrict__ bsums) {
    int i = blockIdx.x * blockDim.x + threadIdx.x;
    if (i < n) rowptr[i + 1] += bsums[i >> 10];
    if (i == 0) rowptr[0] = 0;
}

__global__ void k_fill(const int* __restrict__ srcp, const int* __restrict__ dstp, int n,
                       int* __restrict__ cursor, int* __restrict__ cs) {
    int i = blockIdx.x * blockDim.x + threadIdx.x;
    if (i < n) {
        int p = atomicAdd(&cursor[dstp[i]], 1);
        cs[p] = srcp[i];
    }
}

__global__ void k_dinv(const int* __restrict__ rowptr, float* __restrict__ dinv, int n) {
    int i = blockIdx.x * blockDim.x + threadIdx.x;
    if (i < n) {
        float deg = (float)(rowptr[i + 1] - rowptr[i]) + 1.f;
        dinv[i] = rsqrtf(deg);
    }
}

// ---------------- small GEMM: y[n,32] = x[n,32] @ W[32,32] ----------------
__global__ void k_gemm32(const float* __restrict__ x, const float* __restrict__ W,
                         float* __restrict__ y, int n) {
    __shared__ float Ws[32 * 32];
    __shared__ float xs[8][32];
    int tid = threadIdx.x;
    for (int i = tid; i < 1024; i += 256) Ws[i] = W[i];
    int c = tid & 31, rl = tid >> 5;
    int r = blockIdx.x * 8 + rl;
    if (r < n) xs[rl][c] = x[r * 32 + c];
    __syncthreads();
    if (r < n) {
        float acc = 0.f;
#pragma unroll
        for (int k = 0; k < 32; k++) acc += xs[rl][k] * Ws[k * 32 + c];
        y[r * 32 + c] = acc;
    }
}

// ---------------- fused GCN + GATv2 pull aggregation ----------------
// one 32-lane group per dst node v; lane = feature column
__global__ void k_aggregate(const int* __restrict__ rp_gcn, const int* __restrict__ cs_gcn,
                            const float* __restrict__ h_gcn, const float* __restrict__ dinv,
                            const int* __restrict__ rp_gat, const int* __restrict__ cs_gat,
                            const float* __restrict__ h_gl, const float* __restrict__ h_gr,
                            const float* __restrict__ attv, const float* __restrict__ b_gcn,
                            const float* __restrict__ b_gat, float* __restrict__ out, int n) {
    int tid = threadIdx.x;
    int c = tid & 31;
    int v = blockIdx.x * (blockDim.x >> 5) + (tid >> 5);
    if (v >= n) return;
    float att_c = attv[c];
    // ---- GCN ----
    float acc = 0.f;
    int b0 = rp_gcn[v], e0 = rp_gcn[v + 1];
    float dv = dinv[v];
    for (int e = b0; e < e0; ++e) {
        int s = cs_gcn[e];
        acc += h_gcn[s * 32 + c] * dinv[s];
    }
    acc = acc * dv + h_gcn[v * 32 + c] * dv * dv + b_gcn[c];
    // ---- GATv2 with online softmax ----
    float hr = h_gr[v * 32 + c];
    float m = -3.0e38f, ss = 0.f, o = 0.f;
    int b1 = rp_gat[v], e1 = rp_gat[v + 1];
    for (int e = b1; e < e1; ++e) {
        int s = cs_gat[e];
        float hl = h_gl[s * 32 + c];
        float t = hl + hr;
        t = (t > 0.f) ? t : 0.2f * t;
        float p = t * att_c;
#pragma unroll
        for (int off = 16; off >= 1; off >>= 1) p += __shfl_xor(p, off);
        float mn = fmaxf(m, p);
        float sc = __expf(m - mn);
        float w = __expf(p - mn);
        ss = ss * sc + w;
        o = o * sc + w * hl;
        m = mn;
    }
    out[v * 32 + c] = acc + o / (ss + 1e-16f) + b_gat[c];
}

// ---------------- BatchNorm ----------------
__global__ void k_bn_stats(const float* __restrict__ x, int n, float* __restrict__ stats) {
    __shared__ float sd[256], sd2[256];
    int tid = threadIdx.x, c = tid & 31, rl = tid >> 5;
    float s = 0.f, s2 = 0.f;
    for (int r = blockIdx.x * 8 + rl; r < n; r += gridDim.x * 8) {
        float v = x[r * 32 + c];
        s += v;
        s2 += v * v;
    }
    sd[tid] = s;
    sd2[tid] = s2;
    __syncthreads();
    if (tid < 32) {
        for (int k = 1; k < 8; k++) {
            s += sd[tid + 32 * k];
            s2 += sd2[tid + 32 * k];
        }
        atomicAdd(&stats[c], s);
        atomicAdd(&stats[32 + c], s2);
    }
}

__global__ void k_bn_apply(const float* __restrict__ x, const float* __restrict__ stats,
                           const float* __restrict__ gamma, const float* __restrict__ beta,
                           float* __restrict__ y, int n) {
    int i = blockIdx.x * blockDim.x + threadIdx.x;
    int total = n * 32;
    if (i >= total) return;
    int c = i & 31;
    float inv_n = 1.f / (float)n;
    float mu = stats[c] * inv_n;
    float var = stats[32 + c] * inv_n - mu * mu;
    float g = gamma[c] * rsqrtf(var + 1e-5f);
    float v = g * (x[i] - mu) + beta[c];
    y[i] = (v > 0.f) ? v : 0.f;
}

// ---------------- host ----------------
extern "C" void kernel_launch(void* const* d_in, const int* in_sizes, int n_in, void* d_out,
                              int out_size, void* d_ws, size_t ws_size, hipStream_t stream) {
    const float* x_l = (const float*)d_in[0];
    const float* x_h = (const float*)d_in[1];
    const float* Wll = (const float*)d_in[2];
    const float* bll = (const float*)d_in[3];
    const float* Whh = (const float*)d_in[4];
    const float* bhh = (const float*)d_in[5];
    const float* Whl_l = (const float*)d_in[6];
    const float* Whl_r = (const float*)d_in[7];
    const float* att_hl = (const float*)d_in[8];
    const float* b_hl = (const float*)d_in[9];
    const float* Wlh_l = (const float*)d_in[10];
    const float* Wlh_r = (const float*)d_in[11];
    const float* att_lh = (const float*)d_in[12];
    const float* b_lh = (const float*)d_in[13];
    const float* g_l = (const float*)d_in[14];
    const float* be_l = (const float*)d_in[15];
    const float* g_h = (const float*)d_in[16];
    const float* be_h = (const float*)d_in[17];
    const int* ei_ll = (const int*)d_in[18];
    const int* ei_hh = (const int*)d_in[19];
    const int* ei_hl = (const int*)d_in[20];
    const int* ei_lh = (const int*)d_in[21];

    // workspace carve-up
    char* p = (char*)d_ws;
    auto alloc = [&](size_t bytes) -> void* {
        void* r = (void*)p;
        p += (bytes + 255) & ~(size_t)255;
        return r;
    };
    const size_t FEAT = (size_t)NLOW * 32 * sizeof(float);  // NLOW==NHIGH
    float* hA = (float*)alloc(FEAT);
    float* hB = (float*)alloc(FEAT);
    float* hC = (float*)alloc(FEAT);
    float* new_l = (float*)alloc(FEAT);
    float* new_h = (float*)alloc(FEAT);
    float* xl_buf = (float*)alloc(FEAT);
    float* xh_buf = (float*)alloc(FEAT);
    float* dinv_l = (float*)alloc(NLOW * sizeof(float));
    float* dinv_h = (float*)alloc(NHIGH * sizeof(float));
    float* stats = (float*)alloc(64 * sizeof(float));
    int* rp_ll = (int*)alloc((NLOW + 1) * sizeof(int));
    int* rp_hh = (int*)alloc((NHIGH + 1) * sizeof(int));
    int* rp_hl = (int*)alloc((NLOW + 1) * sizeof(int));
    int* rp_lh = (int*)alloc((NHIGH + 1) * sizeof(int));
    int* cs_ll = (int*)alloc((size_t)EDG * sizeof(int));
    int* cs_hh = (int*)alloc((size_t)EDG * sizeof(int));
    int* cs_hl = (int*)alloc((size_t)EDG * sizeof(int));
    int* cs_lh = (int*)alloc((size_t)EDG * sizeof(int));
    int* counts = (int*)alloc(NLOW * sizeof(int));
    int* cursor = (int*)alloc(NLOW * sizeof(int));
    int* bsums = (int*)alloc(256 * sizeof(int));

    const int TB = 256;
    auto build_csr = [&](const int* ei, int ndst, int* rp, int* cs) {
        const int* srcp = ei;
        const int* dstp = ei + EDG;
        k_zero_i<<<cdiv(ndst, TB), TB, 0, stream>>>(counts, ndst);
        k_count<<<cdiv(EDG, TB), TB, 0, stream>>>(dstp, EDG, counts);
        int B = cdiv(ndst, 1024);
        k_scan1<<<B, TB, 0, stream>>>(counts, ndst, rp, bsums);
        k_scan2<<<1, TB, 0, stream>>>(bsums, B);
        k_scan3<<<cdiv(ndst, TB), TB, 0, stream>>>(rp, ndst, bsums);
        k_copy_i<<<cdiv(ndst, TB), TB, 0, stream>>>(cursor, rp, ndst);
        k_fill<<<cdiv(EDG, TB), TB, 0, stream>>>(srcp, dstp, EDG, cursor, cs);
    };
    build_csr(ei_ll, NLOW, rp_ll, cs_ll);
    build_csr(ei_hh, NHIGH, rp_hh, cs_hh);
    build_csr(ei_hl, NLOW, rp_hl, cs_hl);
    build_csr(ei_lh, NHIGH, rp_lh, cs_lh);
    k_dinv<<<cdiv(NLOW, TB), TB, 0, stream>>>(rp_ll, dinv_l, NLOW);
    k_dinv<<<cdiv(NHIGH, TB), TB, 0, stream>>>(rp_hh, dinv_h, NHIGH);

    const float* cur_l = x_l;
    const float* cur_h = x_h;
    for (int i = 0; i < LAY; i++) {
        const int woff = i * 32 * 32, voff = i * 32;
        // ---- target lowf ----
        k_gemm32<<<cdiv(NLOW, 8), TB, 0, stream>>>(cur_l, Wll + woff, hA, NLOW);
        k_gemm32<<<cdiv(NHIGH, 8), TB, 0, stream>>>(cur_h, Whl_l + woff, hB, NHIGH);
        k_gemm32<<<cdiv(NLOW, 8), TB, 0, stream>>>(cur_l, Whl_r + woff, hC, NLOW);
        k_aggregate<<<cdiv(NLOW, 8), TB, 0, stream>>>(rp_ll, cs_ll, hA, dinv_l, rp_hl, cs_hl, hB,
                                                      hC, att_hl + voff, bll + voff, b_hl + voff,
                                                      new_l, NLOW);
        // ---- target highf ----
        k_gemm32<<<cdiv(NHIGH, 8), TB, 0, stream>>>(cur_h, Whh + woff, hA, NHIGH);
        k_gemm32<<<cdiv(NLOW, 8), TB, 0, stream>>>(cur_l, Wlh_l + woff, hB, NLOW);
        k_gemm32<<<cdiv(NHIGH, 8), TB, 0, stream>>>(cur_h, Wlh_r + woff, hC, NHIGH);
        k_aggregate<<<cdiv(NHIGH, 8), TB, 0, stream>>>(rp_hh, cs_hh, hA, dinv_h, rp_lh, cs_lh, hB,
                                                       hC, att_lh + voff, bhh + voff, b_lh + voff,
                                                       new_h, NHIGH);
        // ---- BN + ReLU ----
        float* out_l = (i == LAY - 1) ? ((float*)d_out) : xl_buf;
        float* out_h = (i == LAY - 1) ? (((float*)d_out) + (size_t)NLOW * 32) : xh_buf;
        k_zero_f<<<1, 64, 0, stream>>>(stats, 64);
        k_bn_stats<<<256, TB, 0, stream>>>(new_l, NLOW, stats);
        k_bn_apply<<<cdiv(NLOW * 32, TB), TB, 0, stream>>>(new_l, stats, g_l + voff, be_l + voff,
                                                           out_l, NLOW);
        k_zero_f<<<1, 64, 0, stream>>>(stats, 64);
        k_bn_stats<<<256, TB, 0, stream>>>(new_h, NHIGH, stats);
        k_bn_apply<<<cdiv(NHIGH * 32, TB), TB, 0, stream>>>(new_h, stats, g_h + voff, be_h + voff,
                                                            out_h, NHIGH);
        cur_l = out_l;
        cur_h = out_h;
    }
}

// Round 2
// 1606.257 us; speedup vs baseline: 1.2264x; 1.2264x over previous
//
#include <hip/hip_runtime.h>
#include <hip/hip_fp16.h>

#define NN 100000      // NLOW == NHIGH
#define EDG 1600000
#define LAY 2

static inline int cdiv(int a, int b) { return (a + b - 1) / b; }

// ---------------- zero init (counts + stats) ----------------
__global__ void k_zero(int* counts, float* stats, int nc, int ns) {
    int i = blockIdx.x * blockDim.x + threadIdx.x;
    if (i < nc) counts[i] = 0;
    if (i < ns) stats[i] = 0.f;
}

// ---------------- CSR build, all 4 relations fused ----------------
__global__ void k_count4(const int* __restrict__ ll, const int* __restrict__ hh,
                         const int* __restrict__ hl, const int* __restrict__ lh,
                         int* __restrict__ counts) {
    int i = blockIdx.x * blockDim.x + threadIdx.x;
    if (i >= 4 * EDG) return;
    int r = i / EDG, e = i - r * EDG;
    const int* dst = (r == 0 ? ll : r == 1 ? hh : r == 2 ? hl : lh) + EDG;
    atomicAdd(&counts[r * NN + dst[e]], 1);
}

#define SCAN_B 98  // cdiv(NN,1024)
__global__ void k_scan1(const int* __restrict__ counts, int* __restrict__ rp,
                        int* __restrict__ bsums) {
    __shared__ int sh[256];
    int r = blockIdx.x / SCAN_B, blk = blockIdx.x - r * SCAN_B;
    const int* in = counts + r * NN;
    int* rowptr = rp + r * (NN + 1);
    int tid = threadIdx.x;
    int base = blk * 1024;
    int v[4];
    int s = 0;
#pragma unroll
    for (int k = 0; k < 4; k++) {
        int idx = base + tid * 4 + k;
        v[k] = (idx < NN) ? in[idx] : 0;
        s += v[k];
    }
    sh[tid] = s;
    __syncthreads();
    for (int off = 1; off < 256; off <<= 1) {
        int t = (tid >= off) ? sh[tid - off] : 0;
        __syncthreads();
        sh[tid] += t;
        __syncthreads();
    }
    int run = (tid > 0) ? sh[tid - 1] : 0;
#pragma unroll
    for (int k = 0; k < 4; k++) {
        int idx = base + tid * 4 + k;
        run += v[k];
        if (idx < NN) rowptr[idx + 1] = run;
    }
    if (tid == 255) bsums[r * 128 + blk] = sh[255];
}

__global__ void k_scan2(int* bsums) {  // 4 blocks, one per relation
    __shared__ int sh[256];
    int tid = threadIdx.x;
    int* b = bsums + blockIdx.x * 128;
    int v = (tid < SCAN_B) ? b[tid] : 0;
    sh[tid] = v;
    __syncthreads();
    for (int off = 1; off < 256; off <<= 1) {
        int t = (tid >= off) ? sh[tid - off] : 0;
        __syncthreads();
        sh[tid] += t;
        __syncthreads();
    }
    if (tid < SCAN_B) b[tid] = sh[tid] - v;  // exclusive
}

__global__ void k_scan3(int* __restrict__ rp, const int* __restrict__ bsums,
                        int* __restrict__ cursor) {
    int i = blockIdx.x * blockDim.x + threadIdx.x;
    if (i >= 4 * NN) return;
    int r = i / NN, j = i - r * NN;
    int val = rp[r * (NN + 1) + j + 1] + bsums[r * 128 + (j >> 10)];
    rp[r * (NN + 1) + j + 1] = val;
    if (j == 0) rp[r * (NN + 1)] = 0;
    // cursor = exclusive start
    int start = (j == 0) ? 0 : 0;  // filled below via separate read
    (void)start;
    cursor[r * NN + j] = val - (rp[r * (NN + 1) + j + 1] - val);  // placeholder, fixed next kernel
}

// simpler & correct: cursor copy after rp final
__global__ void k_cursor(const int* __restrict__ rp, int* __restrict__ cursor) {
    int i = blockIdx.x * blockDim.x + threadIdx.x;
    if (i >= 4 * NN) return;
    int r = i / NN, j = i - r * NN;
    cursor[r * NN + j] = rp[r * (NN + 1) + j];
}

__global__ void k_fill4(const int* __restrict__ ll, const int* __restrict__ hh,
                        const int* __restrict__ hl, const int* __restrict__ lh,
                        int* __restrict__ cursor, int* __restrict__ cs) {
    int i = blockIdx.x * blockDim.x + threadIdx.x;
    if (i >= 4 * EDG) return;
    int r = i / EDG, e = i - r * EDG;
    const int* ei = (r == 0 ? ll : r == 1 ? hh : r == 2 ? hl : lh);
    int s = ei[e], d = ei[EDG + e];
    int p = atomicAdd(&cursor[r * NN + d], 1);
    cs[(size_t)r * EDG + p] = s;
}

__global__ void k_dinv(const int* __restrict__ rp, float* __restrict__ dinv_l,
                       float* __restrict__ dinv_h) {
    int i = blockIdx.x * blockDim.x + threadIdx.x;
    if (i >= 2 * NN) return;
    int r = (i < NN) ? 0 : 1, j = (i < NN) ? i : i - NN;
    const int* rpr = rp + r * (NN + 1);
    float deg = (float)(rpr[j + 1] - rpr[j]) + 1.f;
    float v = rsqrtf(deg);
    if (r == 0) dinv_l[j] = v; else dinv_h[j] = v;
}

// ---------------- fused 3-output GEMM: y_i[n,32] = x[n,32] @ W_i, fp16 out ----------------
__global__ __launch_bounds__(256) void k_gemm3(const float* __restrict__ x,
                                               const float* __restrict__ W0,
                                               const float* __restrict__ W1,
                                               const float* __restrict__ W2,
                                               __half* __restrict__ y0, __half* __restrict__ y1,
                                               __half* __restrict__ y2, int n) {
    __shared__ float Ws[3][1024];
    __shared__ float xs[8][32];
    int tid = threadIdx.x;
    for (int i = tid; i < 1024; i += 256) {
        Ws[0][i] = W0[i];
        Ws[1][i] = W1[i];
        Ws[2][i] = W2[i];
    }
    int c = tid & 31, rl = tid >> 5;
    for (int r0 = blockIdx.x * 8; r0 < n; r0 += gridDim.x * 8) {
        int r = r0 + rl;
        __syncthreads();
        if (r < n) xs[rl][c] = x[(size_t)r * 32 + c];
        __syncthreads();
        if (r < n) {
            float a0 = 0.f, a1 = 0.f, a2 = 0.f;
#pragma unroll
            for (int k = 0; k < 32; k++) {
                float xv = xs[rl][k];
                a0 += xv * Ws[0][k * 32 + c];
                a1 += xv * Ws[1][k * 32 + c];
                a2 += xv * Ws[2][k * 32 + c];
            }
            y0[(size_t)r * 32 + c] = __float2half(a0);
            y1[(size_t)r * 32 + c] = __float2half(a1);
            y2[(size_t)r * 32 + c] = __float2half(a2);
        }
    }
}

// ---------------- fused GCN + GATv2 pull aggregation + BN-stats epilogue ----------------
__global__ __launch_bounds__(256) void k_aggregate(
    const int* __restrict__ rp_gcn, const int* __restrict__ cs_gcn,
    const __half* __restrict__ h_gcn, const float* __restrict__ dinv,
    const int* __restrict__ rp_gat, const int* __restrict__ cs_gat,
    const __half* __restrict__ h_gl, const __half* __restrict__ h_gr,
    const float* __restrict__ attv, const float* __restrict__ b_gcn,
    const float* __restrict__ b_gat, float* __restrict__ out, float* __restrict__ stats, int n) {
    int tid = threadIdx.x;
    int c = tid & 31, g = tid >> 5;
    float att_c = attv[c];
    float bsum = b_gcn[c] + b_gat[c];
    float s1 = 0.f, s2 = 0.f;
    for (int v = blockIdx.x * 8 + g; v < n; v += gridDim.x * 8) {
        // ---- GCN ----
        float acc = 0.f;
        int b0 = rp_gcn[v], e0 = rp_gcn[v + 1];
        float dv = dinv[v];
        for (int e = b0; e < e0; ++e) {
            int s = cs_gcn[e];
            acc += __half2float(h_gcn[(size_t)s * 32 + c]) * dinv[s];
        }
        acc = acc * dv + __half2float(h_gcn[(size_t)v * 32 + c]) * dv * dv;
        // ---- GATv2, online softmax, 2-edge unroll ----
        float hr = __half2float(h_gr[(size_t)v * 32 + c]);
        float m = -3.0e38f, ss = 0.f, o = 0.f;
        int b1 = rp_gat[v], e1 = rp_gat[v + 1];
        int e = b1;
        for (; e + 1 < e1; e += 2) {
            int sA = cs_gat[e], sB = cs_gat[e + 1];
            float hlA = __half2float(h_gl[(size_t)sA * 32 + c]);
            float hlB = __half2float(h_gl[(size_t)sB * 32 + c]);
            float tA = hlA + hr; tA = (tA > 0.f) ? tA : 0.2f * tA;
            float tB = hlB + hr; tB = (tB > 0.f) ? tB : 0.2f * tB;
            float pA = tA * att_c, pB = tB * att_c;
#pragma unroll
            for (int off = 16; off >= 1; off >>= 1) {
                pA += __shfl_xor(pA, off);
                pB += __shfl_xor(pB, off);
            }
            float pm = fmaxf(pA, pB);
            float mn = fmaxf(m, pm);
            float sc = __expf(m - mn);
            float wA = __expf(pA - mn), wB = __expf(pB - mn);
            ss = ss * sc + wA + wB;
            o = o * sc + wA * hlA + wB * hlB;
            m = mn;
        }
        if (e < e1) {
            int s = cs_gat[e];
            float hl = __half2float(h_gl[(size_t)s * 32 + c]);
            float t = hl + hr; t = (t > 0.f) ? t : 0.2f * t;
            float p = t * att_c;
#pragma unroll
            for (int off = 16; off >= 1; off >>= 1) p += __shfl_xor(p, off);
            float mn = fmaxf(m, p);
            float sc = __expf(m - mn), w = __expf(p - mn);
            ss = ss * sc + w;
            o = o * sc + w * hl;
            m = mn;
        }
        float res = acc + o / (ss + 1e-16f) + bsum;
        out[(size_t)v * 32 + c] = res;
        s1 += res;
        s2 += res * res;
    }
    __shared__ float sd[256], sq[256];
    sd[tid] = s1;
    sq[tid] = s2;
    __syncthreads();
    if (tid < 32) {
#pragma unroll
        for (int k = 1; k < 8; k++) {
            s1 += sd[tid + 32 * k];
            s2 += sq[tid + 32 * k];
        }
        atomicAdd(&stats[c], s1);
        atomicAdd(&stats[32 + c], s2);
    }
}

// ---------------- BN apply + ReLU ----------------
__global__ void k_bn_apply(const float* __restrict__ x, const float* __restrict__ stats,
                           const float* __restrict__ gamma, const float* __restrict__ beta,
                           float* __restrict__ y, int n) {
    int total = n * 32;
    float inv_n = 1.f / (float)n;
    for (int i = blockIdx.x * blockDim.x + threadIdx.x; i < total; i += gridDim.x * blockDim.x) {
        int c = i & 31;
        float mu = stats[c] * inv_n;
        float var = stats[32 + c] * inv_n - mu * mu;
        float gs = gamma[c] * rsqrtf(var + 1e-5f);
        float v = gs * (x[i] - mu) + beta[c];
        y[i] = (v > 0.f) ? v : 0.f;
    }
}

// ---------------- host ----------------
extern "C" void kernel_launch(void* const* d_in, const int* in_sizes, int n_in, void* d_out,
                              int out_size, void* d_ws, size_t ws_size, hipStream_t stream) {
    const float* x_l = (const float*)d_in[0];
    const float* x_h = (const float*)d_in[1];
    const float* Wll = (const float*)d_in[2];
    const float* bll = (const float*)d_in[3];
    const float* Whh = (const float*)d_in[4];
    const float* bhh = (const float*)d_in[5];
    const float* Whl_l = (const float*)d_in[6];
    const float* Whl_r = (const float*)d_in[7];
    const float* att_hl = (const float*)d_in[8];
    const float* b_hl = (const float*)d_in[9];
    const float* Wlh_l = (const float*)d_in[10];
    const float* Wlh_r = (const float*)d_in[11];
    const float* att_lh = (const float*)d_in[12];
    const float* b_lh = (const float*)d_in[13];
    const float* g_l = (const float*)d_in[14];
    const float* be_l = (const float*)d_in[15];
    const float* g_h = (const float*)d_in[16];
    const float* be_h = (const float*)d_in[17];
    const int* ei_ll = (const int*)d_in[18];
    const int* ei_hh = (const int*)d_in[19];
    const int* ei_hl = (const int*)d_in[20];
    const int* ei_lh = (const int*)d_in[21];

    char* p = (char*)d_ws;
    auto alloc = [&](size_t bytes) -> void* {
        void* r = (void*)p;
        p += (bytes + 255) & ~(size_t)255;
        return r;
    };
    const size_t HFEAT = (size_t)NN * 32 * sizeof(__half);
    const size_t FFEAT = (size_t)NN * 32 * sizeof(float);
    __half* hgcn_l = (__half*)alloc(HFEAT);
    __half* hgcn_h = (__half*)alloc(HFEAT);
    __half* hgl_hl = (__half*)alloc(HFEAT);  // x_h @ Whl_l
    __half* hgr_hl = (__half*)alloc(HFEAT);  // x_l @ Whl_r
    __half* hgl_lh = (__half*)alloc(HFEAT);  // x_l @ Wlh_l
    __half* hgr_lh = (__half*)alloc(HFEAT);  // x_h @ Wlh_r
    float* new_l = (float*)alloc(FFEAT);
    float* new_h = (float*)alloc(FFEAT);
    float* xl_buf = (float*)alloc(FFEAT);
    float* xh_buf = (float*)alloc(FFEAT);
    float* dinv_l = (float*)alloc(NN * sizeof(float));
    float* dinv_h = (float*)alloc(NN * sizeof(float));
    float* stats = (float*)alloc(4 * 64 * sizeof(float));  // per (layer,type)
    int* rp = (int*)alloc((size_t)4 * (NN + 1) * sizeof(int));
    int* counts = (int*)alloc((size_t)4 * NN * sizeof(int));
    int* cursor = (int*)alloc((size_t)4 * NN * sizeof(int));
    int* cs = (int*)alloc((size_t)4 * EDG * sizeof(int));
    int* bsums = (int*)alloc(4 * 128 * sizeof(int));

    const int TB = 256;
    // CSR build (all relations fused)
    k_zero<<<cdiv(4 * NN, TB), TB, 0, stream>>>(counts, stats, 4 * NN, 4 * 64);
    k_count4<<<cdiv(4 * EDG, TB), TB, 0, stream>>>(ei_ll, ei_hh, ei_hl, ei_lh, counts);
    k_scan1<<<4 * SCAN_B, TB, 0, stream>>>(counts, rp, bsums);
    k_scan2<<<4, TB, 0, stream>>>(bsums);
    // finalize rp (+cursor in second pass for correctness)
    {
        // reuse k_scan3 only for rp offset add
        k_scan3<<<cdiv(4 * NN, TB), TB, 0, stream>>>(rp, bsums, cursor);
        k_cursor<<<cdiv(4 * NN, TB), TB, 0, stream>>>(rp, cursor);
    }
    k_fill4<<<cdiv(4 * EDG, TB), TB, 0, stream>>>(ei_ll, ei_hh, ei_hl, ei_lh, cursor, cs);
    k_dinv<<<cdiv(2 * NN, TB), TB, 0, stream>>>(rp, dinv_l, dinv_h);

    const int* rp0 = rp;                  // ll
    const int* rp1 = rp + (NN + 1);       // hh
    const int* rp2 = rp + 2 * (NN + 1);   // hl
    const int* rp3 = rp + 3 * (NN + 1);   // lh
    const int* cs0 = cs;
    const int* cs1 = cs + (size_t)EDG;
    const int* cs2 = cs + (size_t)2 * EDG;
    const int* cs3 = cs + (size_t)3 * EDG;

    const float* cur_l = x_l;
    const float* cur_h = x_h;
    const int GRID = 2048;
    for (int i = 0; i < LAY; i++) {
        const int woff = i * 32 * 32, voff = i * 32;
        // projections: lowf input -> {gcn_ll, gat_hl right, gat_lh left}
        k_gemm3<<<GRID, TB, 0, stream>>>(cur_l, Wll + woff, Whl_r + woff, Wlh_l + woff, hgcn_l,
                                         hgr_hl, hgl_lh, NN);
        // highf input -> {gcn_hh, gat_lh right, gat_hl left}
        k_gemm3<<<GRID, TB, 0, stream>>>(cur_h, Whh + woff, Wlh_r + woff, Whl_l + woff, hgcn_h,
                                         hgr_lh, hgl_hl, NN);
        float* st_l = stats + (i * 2 + 0) * 64;
        float* st_h = stats + (i * 2 + 1) * 64;
        k_aggregate<<<GRID, TB, 0, stream>>>(rp0, cs0, hgcn_l, dinv_l, rp2, cs2, hgl_hl, hgr_hl,
                                             att_hl + voff, bll + voff, b_hl + voff, new_l, st_l,
                                             NN);
        k_aggregate<<<GRID, TB, 0, stream>>>(rp1, cs1, hgcn_h, dinv_h, rp3, cs3, hgl_lh, hgr_lh,
                                             att_lh + voff, bhh + voff, b_lh + voff, new_h, st_h,
                                             NN);
        float* out_l = (i == LAY - 1) ? ((float*)d_out) : xl_buf;
        float* out_h = (i == LAY - 1) ? (((float*)d_out) + (size_t)NN * 32) : xh_buf;
        k_bn_apply<<<GRID, TB, 0, stream>>>(new_l, st_l, g_l + voff, be_l + voff, out_l, NN);
        k_bn_apply<<<GRID, TB, 0, stream>>>(new_h, st_h, g_h + voff, be_h + voff, out_h, NN);
        cur_l = out_l;
        cur_h = out_h;
    }
}

// Round 3
// 1056.981 us; speedup vs baseline: 1.8637x; 1.5197x over previous
//
#include <hip/hip_runtime.h>
#include <hip/hip_fp16.h>

#define NN 100000
#define EDG 1600000
#define LAY 2
#define NBKT 98      // ceil(NN / 1024)
#define BKTPAD 128
#define CAP 18432    // LDS sort capacity per bucket (avg 16384, sigma~127)
#define PCHUNK 2560  // edges per partition block (256 thr x 10)
#define CPR 625      // EDG / PCHUNK (exact)

static inline int cdiv(int a, int b) { return (a + b - 1) / b; }

// ---------------- init ----------------
__global__ void k_init(int* bhist, float* stats) {
    int t = blockIdx.x * blockDim.x + threadIdx.x;
    if (t < 4 * BKTPAD) bhist[t] = 0;
    if (t < 4 * 64) stats[t] = 0.f;
}

// ---------------- coarse bucket histogram ----------------
__global__ __launch_bounds__(256) void k_bhist(const int* __restrict__ ll,
                                               const int* __restrict__ hh,
                                               const int* __restrict__ hl,
                                               const int* __restrict__ lh, int* __restrict__ bhist) {
    __shared__ int h[NBKT];
    int tid = threadIdx.x;
    if (tid < NBKT) h[tid] = 0;
    __syncthreads();
    int r = blockIdx.x / CPR;
    int chunk = blockIdx.x - r * CPR;
    const int* dst = (r == 0 ? ll : r == 1 ? hh : r == 2 ? hl : lh) + EDG;
    int base = chunk * PCHUNK;
#pragma unroll
    for (int k = 0; k < 10; k++) {
        int d = dst[base + k * 256 + tid];
        atomicAdd(&h[d >> 10], 1);
    }
    __syncthreads();
    if (tid < NBKT) atomicAdd(&bhist[r * BKTPAD + tid], h[tid]);
}

// ---------------- tiny scan of bucket counts ----------------
__global__ void k_bscan(const int* __restrict__ bhist, int* __restrict__ bases,
                        int* __restrict__ gcursor, int* __restrict__ rp) {
    __shared__ int sh[BKTPAD];
    int t = threadIdx.x;
    for (int r = 0; r < 4; r++) {
        int v = (t < BKTPAD) ? ((t < NBKT) ? bhist[r * BKTPAD + t] : 0) : 0;
        if (t < BKTPAD) sh[t] = v;
        __syncthreads();
        for (int off = 1; off < BKTPAD; off <<= 1) {
            int x = (t < BKTPAD && t >= off) ? sh[t - off] : 0;
            __syncthreads();
            if (t < BKTPAD) sh[t] += x;
            __syncthreads();
        }
        if (t < BKTPAD) {
            int ex = sh[t] - v;
            bases[r * BKTPAD + t] = ex;
            gcursor[r * BKTPAD + t] = ex;
        }
        __syncthreads();
    }
    if (t < 4) rp[t * (NN + 1) + NN] = EDG;
}

// ---------------- partition edges into coarse buckets (coalesced runs) ----------------
__global__ __launch_bounds__(256) void k_partition(const int* __restrict__ ll,
                                                   const int* __restrict__ hh,
                                                   const int* __restrict__ hl,
                                                   const int* __restrict__ lh,
                                                   int* __restrict__ gcursor,
                                                   int2* __restrict__ pairs) {
    __shared__ int lhist[NBKT], lbase[NBKT];
    int tid = threadIdx.x;
    if (tid < NBKT) lhist[tid] = 0;
    __syncthreads();
    int r = blockIdx.x / CPR;
    int chunk = blockIdx.x - r * CPR;
    const int* ei = (r == 0 ? ll : r == 1 ? hh : r == 2 ? hl : lh);
    const int* srcp = ei;
    const int* dstp = ei + EDG;
    int base = chunk * PCHUNK;
    int s[10], d[10], rk[10];
#pragma unroll
    for (int k = 0; k < 10; k++) {
        int e = base + k * 256 + tid;
        s[k] = srcp[e];
        d[k] = dstp[e];
        rk[k] = atomicAdd(&lhist[d[k] >> 10], 1);
    }
    __syncthreads();
    if (tid < NBKT) lbase[tid] = atomicAdd(&gcursor[r * BKTPAD + tid], lhist[tid]);
    __syncthreads();
    int2* pr = pairs + (size_t)r * EDG;
#pragma unroll
    for (int k = 0; k < 10; k++) {
        int b = d[k] >> 10;
        pr[lbase[b] + rk[k]] = make_int2(s[k], d[k]);
    }
}

// ---------------- per-bucket CSR finalize: rowptr + coalesced cs ----------------
__global__ __launch_bounds__(256) void k_build(const int2* __restrict__ pairs,
                                               const int* __restrict__ bases,
                                               const int* __restrict__ bhist, int* __restrict__ rp,
                                               int* __restrict__ cs) {
    __shared__ int cnt_arr[1024];
    __shared__ int sh[256];
    __shared__ int srcs[CAP];
    int tid = threadIdx.x;
    int r = blockIdx.x / NBKT;
    int b = blockIdx.x - r * NBKT;
    int base = bases[r * BKTPAD + b];
    int cnt = bhist[r * BKTPAD + b];
    int d0 = b << 10;
    int ndst = NN - d0;
    if (ndst > 1024) ndst = 1024;
#pragma unroll
    for (int j = 0; j < 4; j++) cnt_arr[4 * tid + j] = 0;
    __syncthreads();
    const int2* pr = pairs + (size_t)r * EDG + base;
    for (int i = tid; i < cnt; i += 256) {
        int2 p = pr[i];
        atomicAdd(&cnt_arr[p.y - d0], 1);
    }
    __syncthreads();
    int c0 = cnt_arr[4 * tid], c1 = cnt_arr[4 * tid + 1], c2 = cnt_arr[4 * tid + 2],
        c3 = cnt_arr[4 * tid + 3];
    int s = c0 + c1 + c2 + c3;
    sh[tid] = s;
    __syncthreads();
    for (int off = 1; off < 256; off <<= 1) {
        int x = (tid >= off) ? sh[tid - off] : 0;
        __syncthreads();
        sh[tid] += x;
        __syncthreads();
    }
    int run = sh[tid] - s;
    int st0 = run, st1 = st0 + c0, st2 = st1 + c1, st3 = st2 + c2;
    cnt_arr[4 * tid] = st0;
    cnt_arr[4 * tid + 1] = st1;
    cnt_arr[4 * tid + 2] = st2;
    cnt_arr[4 * tid + 3] = st3;
    int* rpr = rp + r * (NN + 1);
    if (4 * tid + 0 < ndst) rpr[d0 + 4 * tid + 0] = base + st0;
    if (4 * tid + 1 < ndst) rpr[d0 + 4 * tid + 1] = base + st1;
    if (4 * tid + 2 < ndst) rpr[d0 + 4 * tid + 2] = base + st2;
    if (4 * tid + 3 < ndst) rpr[d0 + 4 * tid + 3] = base + st3;
    __syncthreads();
    for (int i = tid; i < cnt; i += 256) {
        int2 p = pr[i];
        int pos = atomicAdd(&cnt_arr[p.y - d0], 1);
        if (pos < CAP) srcs[pos] = p.x;
    }
    __syncthreads();
    int* csr = cs + (size_t)r * EDG + base;
    for (int i = tid; i < cnt; i += 256) csr[i] = (i < CAP) ? srcs[i] : 0;
}

__global__ void k_dinv(const int* __restrict__ rp, float* __restrict__ dinv_l,
                       float* __restrict__ dinv_h) {
    int i = blockIdx.x * blockDim.x + threadIdx.x;
    if (i >= 2 * NN) return;
    int r = (i < NN) ? 0 : 1, j = (i < NN) ? i : i - NN;
    const int* rpr = rp + r * (NN + 1);
    float deg = (float)(rpr[j + 1] - rpr[j]) + 1.f;
    float v = rsqrtf(deg);
    if (r == 0) dinv_l[j] = v;
    else dinv_h[j] = v;
}

// ---------------- fused (optional BN+ReLU input) 3-output GEMM, y0 pre-scaled by dinv ----------------
__global__ __launch_bounds__(256) void k_gemm3(const float* __restrict__ x,
                                               const float* __restrict__ stats,
                                               const float* __restrict__ gamma,
                                               const float* __restrict__ beta,
                                               const float* __restrict__ W0,
                                               const float* __restrict__ W1,
                                               const float* __restrict__ W2,
                                               const float* __restrict__ scale0,
                                               __half* __restrict__ y0, __half* __restrict__ y1,
                                               __half* __restrict__ y2) {
    __shared__ float Ws[3][1024];
    __shared__ float xs[8][32];
    int tid = threadIdx.x;
    for (int i = tid; i < 1024; i += 256) {
        Ws[0][i] = W0[i];
        Ws[1][i] = W1[i];
        Ws[2][i] = W2[i];
    }
    int c = tid & 31, rl = tid >> 5;
    float mu = 0.f, gs = 1.f, be = 0.f;
    if (stats) {
        const float inv_n = 1.f / (float)NN;
        mu = stats[c] * inv_n;
        float var = stats[32 + c] * inv_n - mu * mu;
        gs = gamma[c] * rsqrtf(var + 1e-5f);
        be = beta[c];
    }
    for (int r0 = blockIdx.x * 8; r0 < NN; r0 += gridDim.x * 8) {
        int r = r0 + rl;
        __syncthreads();
        if (r < NN) {
            float xv = x[(size_t)r * 32 + c];
            if (stats) {
                xv = gs * (xv - mu) + be;
                xv = (xv > 0.f) ? xv : 0.f;
            }
            xs[rl][c] = xv;
        }
        __syncthreads();
        if (r < NN) {
            float a0 = 0.f, a1 = 0.f, a2 = 0.f;
#pragma unroll
            for (int k = 0; k < 32; k++) {
                float xv = xs[rl][k];
                a0 += xv * Ws[0][k * 32 + c];
                a1 += xv * Ws[1][k * 32 + c];
                a2 += xv * Ws[2][k * 32 + c];
            }
            a0 *= scale0[r];
            y0[(size_t)r * 32 + c] = __float2half(a0);
            y1[(size_t)r * 32 + c] = __float2half(a1);
            y2[(size_t)r * 32 + c] = __float2half(a2);
        }
    }
}

// ---------------- fused GCN + GATv2 pull aggregation + BN-stats epilogue ----------------
__global__ __launch_bounds__(256) void k_aggregate(
    const int* __restrict__ rp_gcn, const int* __restrict__ cs_gcn,
    const __half* __restrict__ h_gcn, const float* __restrict__ dinv,
    const int* __restrict__ rp_gat, const int* __restrict__ cs_gat,
    const __half* __restrict__ h_gl, const __half* __restrict__ h_gr,
    const float* __restrict__ attv, const float* __restrict__ b_gcn,
    const float* __restrict__ b_gat, float* __restrict__ out, float* __restrict__ stats) {
    int tid = threadIdx.x;
    int c = tid & 31, g = tid >> 5;
    float att_c = attv[c];
    float bsum = b_gcn[c] + b_gat[c];
    float s1 = 0.f, s2 = 0.f;
    for (int v = blockIdx.x * 8 + g; v < NN; v += gridDim.x * 8) {
        // ---- GCN (h pre-scaled by dinv[src]) ----
        float acc = 0.f;
        int b0 = rp_gcn[v], e0 = rp_gcn[v + 1];
        float dv = dinv[v];
        for (int e = b0; e < e0; ++e) {
            int s = cs_gcn[e];
            acc += __half2float(h_gcn[(size_t)s * 32 + c]);
        }
        acc = (acc + __half2float(h_gcn[(size_t)v * 32 + c])) * dv;
        // ---- GATv2, online softmax, 2-edge unroll ----
        float hr = __half2float(h_gr[(size_t)v * 32 + c]);
        float m = -3.0e38f, ss = 0.f, o = 0.f;
        int b1 = rp_gat[v], e1 = rp_gat[v + 1];
        int e = b1;
        for (; e + 1 < e1; e += 2) {
            int sA = cs_gat[e], sB = cs_gat[e + 1];
            float hlA = __half2float(h_gl[(size_t)sA * 32 + c]);
            float hlB = __half2float(h_gl[(size_t)sB * 32 + c]);
            float tA = hlA + hr;
            tA = (tA > 0.f) ? tA : 0.2f * tA;
            float tB = hlB + hr;
            tB = (tB > 0.f) ? tB : 0.2f * tB;
            float pA = tA * att_c, pB = tB * att_c;
#pragma unroll
            for (int off = 16; off >= 1; off >>= 1) {
                pA += __shfl_xor(pA, off);
                pB += __shfl_xor(pB, off);
            }
            float pm = fmaxf(pA, pB);
            float mn = fmaxf(m, pm);
            float sc = __expf(m - mn);
            float wA = __expf(pA - mn), wB = __expf(pB - mn);
            ss = ss * sc + wA + wB;
            o = o * sc + wA * hlA + wB * hlB;
            m = mn;
        }
        if (e < e1) {
            int sA = cs_gat[e];
            float hl = __half2float(h_gl[(size_t)sA * 32 + c]);
            float t = hl + hr;
            t = (t > 0.f) ? t : 0.2f * t;
            float p = t * att_c;
#pragma unroll
            for (int off = 16; off >= 1; off >>= 1) p += __shfl_xor(p, off);
            float mn = fmaxf(m, p);
            float sc = __expf(m - mn), w = __expf(p - mn);
            ss = ss * sc + w;
            o = o * sc + w * hl;
            m = mn;
        }
        float res = acc + o / (ss + 1e-16f) + bsum;
        out[(size_t)v * 32 + c] = res;
        s1 += res;
        s2 += res * res;
    }
    __shared__ float sd[256], sq[256];
    sd[tid] = s1;
    sq[tid] = s2;
    __syncthreads();
    if (tid < 32) {
#pragma unroll
        for (int k = 1; k < 8; k++) {
            s1 += sd[tid + 32 * k];
            s2 += sq[tid + 32 * k];
        }
        atomicAdd(&stats[c], s1);
        atomicAdd(&stats[32 + c], s2);
    }
}

// ---------------- final BN apply + ReLU ----------------
__global__ void k_bn_apply(const float* __restrict__ x, const float* __restrict__ stats,
                           const float* __restrict__ gamma, const float* __restrict__ beta,
                           float* __restrict__ y) {
    int total = NN * 32;
    const float inv_n = 1.f / (float)NN;
    for (int i = blockIdx.x * blockDim.x + threadIdx.x; i < total; i += gridDim.x * blockDim.x) {
        int c = i & 31;
        float mu = stats[c] * inv_n;
        float var = stats[32 + c] * inv_n - mu * mu;
        float gs = gamma[c] * rsqrtf(var + 1e-5f);
        float v = gs * (x[i] - mu) + beta[c];
        y[i] = (v > 0.f) ? v : 0.f;
    }
}

// ---------------- host ----------------
extern "C" void kernel_launch(void* const* d_in, const int* in_sizes, int n_in, void* d_out,
                              int out_size, void* d_ws, size_t ws_size, hipStream_t stream) {
    const float* x_l = (const float*)d_in[0];
    const float* x_h = (const float*)d_in[1];
    const float* Wll = (const float*)d_in[2];
    const float* bll = (const float*)d_in[3];
    const float* Whh = (const float*)d_in[4];
    const float* bhh = (const float*)d_in[5];
    const float* Whl_l = (const float*)d_in[6];
    const float* Whl_r = (const float*)d_in[7];
    const float* att_hl = (const float*)d_in[8];
    const float* b_hl = (const float*)d_in[9];
    const float* Wlh_l = (const float*)d_in[10];
    const float* Wlh_r = (const float*)d_in[11];
    const float* att_lh = (const float*)d_in[12];
    const float* b_lh = (const float*)d_in[13];
    const float* g_l = (const float*)d_in[14];
    const float* be_l = (const float*)d_in[15];
    const float* g_h = (const float*)d_in[16];
    const float* be_h = (const float*)d_in[17];
    const int* ei_ll = (const int*)d_in[18];
    const int* ei_hh = (const int*)d_in[19];
    const int* ei_hl = (const int*)d_in[20];
    const int* ei_lh = (const int*)d_in[21];

    char* p = (char*)d_ws;
    auto alloc = [&](size_t bytes) -> void* {
        void* r = (void*)p;
        p += (bytes + 255) & ~(size_t)255;
        return r;
    };
    const size_t HFEAT = (size_t)NN * 32 * sizeof(__half);
    const size_t FFEAT = (size_t)NN * 32 * sizeof(float);
    // pairs region (51.2 MB), unioned with new_l/new_h (25.6 MB) — pairs dead after k_build
    int2* pairs = (int2*)alloc((size_t)4 * EDG * sizeof(int2));
    float* new_l = (float*)pairs;
    float* new_h = (float*)((char*)pairs + FFEAT);
    __half* hgcn_l = (__half*)alloc(HFEAT);
    __half* hgcn_h = (__half*)alloc(HFEAT);
    __half* hgl_hl = (__half*)alloc(HFEAT);
    __half* hgr_hl = (__half*)alloc(HFEAT);
    __half* hgl_lh = (__half*)alloc(HFEAT);
    __half* hgr_lh = (__half*)alloc(HFEAT);
    int* cs = (int*)alloc((size_t)4 * EDG * sizeof(int));
    int* rp = (int*)alloc((size_t)4 * (NN + 1) * sizeof(int));
    float* dinv_l = (float*)alloc(NN * sizeof(float));
    float* dinv_h = (float*)alloc(NN * sizeof(float));
    int* bhist = (int*)alloc(4 * BKTPAD * sizeof(int));
    int* bases = (int*)alloc(4 * BKTPAD * sizeof(int));
    int* gcursor = (int*)alloc(4 * BKTPAD * sizeof(int));
    float* stats = (float*)alloc(4 * 64 * sizeof(float));

    const int TB = 256;
    k_init<<<2, TB, 0, stream>>>(bhist, stats);
    k_bhist<<<4 * CPR, TB, 0, stream>>>(ei_ll, ei_hh, ei_hl, ei_lh, bhist);
    k_bscan<<<1, TB, 0, stream>>>(bhist, bases, gcursor, rp);
    k_partition<<<4 * CPR, TB, 0, stream>>>(ei_ll, ei_hh, ei_hl, ei_lh, gcursor, pairs);
    k_build<<<4 * NBKT, TB, 0, stream>>>(pairs, bases, bhist, rp, cs);
    k_dinv<<<cdiv(2 * NN, TB), TB, 0, stream>>>(rp, dinv_l, dinv_h);

    const int* rp0 = rp;
    const int* rp1 = rp + (NN + 1);
    const int* rp2 = rp + 2 * (NN + 1);
    const int* rp3 = rp + 3 * (NN + 1);
    const int* cs0 = cs;
    const int* cs1 = cs + (size_t)EDG;
    const int* cs2 = cs + (size_t)2 * EDG;
    const int* cs3 = cs + (size_t)3 * EDG;

    const int GRID = 2048;
    float* st0l = stats;
    float* st0h = stats + 64;
    float* st1l = stats + 128;
    float* st1h = stats + 192;

    // ---- layer 0 ----
    k_gemm3<<<GRID, TB, 0, stream>>>(x_l, nullptr, nullptr, nullptr, Wll, Whl_r, Wlh_l, dinv_l,
                                     hgcn_l, hgr_hl, hgl_lh);
    k_gemm3<<<GRID, TB, 0, stream>>>(x_h, nullptr, nullptr, nullptr, Whh, Wlh_r, Whl_l, dinv_h,
                                     hgcn_h, hgr_lh, hgl_hl);
    k_aggregate<<<GRID, TB, 0, stream>>>(rp0, cs0, hgcn_l, dinv_l, rp2, cs2, hgl_hl, hgr_hl,
                                         att_hl, bll, b_hl, new_l, st0l);
    k_aggregate<<<GRID, TB, 0, stream>>>(rp1, cs1, hgcn_h, dinv_h, rp3, cs3, hgl_lh, hgr_lh,
                                         att_lh, bhh, b_lh, new_h, st0h);
    // ---- layer 1 (BN+ReLU of layer-0 fused into GEMM input load) ----
    k_gemm3<<<GRID, TB, 0, stream>>>(new_l, st0l, g_l, be_l, Wll + 1024, Whl_r + 1024,
                                     Wlh_l + 1024, dinv_l, hgcn_l, hgr_hl, hgl_lh);
    k_gemm3<<<GRID, TB, 0, stream>>>(new_h, st0h, g_h, be_h, Whh + 1024, Wlh_r + 1024,
                                     Whl_l + 1024, dinv_h, hgcn_h, hgr_lh, hgl_hl);
    k_aggregate<<<GRID, TB, 0, stream>>>(rp0, cs0, hgcn_l, dinv_l, rp2, cs2, hgl_hl, hgr_hl,
                                         att_hl + 32, bll + 32, b_hl + 32, new_l, st1l);
    k_aggregate<<<GRID, TB, 0, stream>>>(rp1, cs1, hgcn_h, dinv_h, rp3, cs3, hgl_lh, hgr_lh,
                                         att_lh + 32, bhh + 32, b_lh + 32, new_h, st1h);
    // ---- final BN + ReLU -> d_out ----
    k_bn_apply<<<GRID, TB, 0, stream>>>(new_l, st1l, g_l + 32, be_l + 32, (float*)d_out);
    k_bn_apply<<<GRID, TB, 0, stream>>>(new_h, st1h, g_h + 32, be_h + 32,
                                        ((float*)d_out) + (size_t)NN * 32);
}